// Round 17
// baseline (38.977 us; speedup 1.0000x reference)
//
#include <hip/hip_runtime.h>

// LIF forward scan, B=65536 rows x L=400 steps.
// Outputs (concatenated float32 in d_out):
//   [0,              B*L)    spikes (exactly 0.0/1.0)
//   [B*L,        B*L + B)    hard_latency (first spike index, or L) as float
//   [B*L + B,  B*L + 2*B)    soft_latency = sum(s*t) / (sum(s) + 1e-6)
//
// R16 = R15 with the race fixed. R15's vmcnt(10) proof assumed issue order
// [dma][stores] per phase; the scheduler could emit stores first, leaving
// DMA outstanding across the barrier (sparse spike flips -> soft-latency
// fail). Fix: __builtin_amdgcn_sched_barrier(0) pins {dma | stores | wait}
// ordering. Ledger per phase: [<=10 old stores][10 dma][10 new stores];
// vmcnt retires in issue order (m135) => vmcnt(10) guarantees dma done,
// newest stores stay in flight across the barrier.

constexpr int Bsz  = 65536;
constexpr int Lsz  = 400;
constexpr int ROWS = 64;            // rows per block (one per compute lane)
constexpr int TC   = 40;            // timesteps per chunk (phase)
constexpr int V4   = TC / 4;        // 10 float4 per chunk per row

typedef float floatx4 __attribute__((ext_vector_type(4)));

// raw barriers with explicit wait semantics:
#define BAR_VM0()  asm volatile("s_waitcnt vmcnt(0) lgkmcnt(0)\n\ts_barrier" ::: "memory")
#define BAR_VM10() asm volatile("s_waitcnt vmcnt(10) lgkmcnt(0)\n\ts_barrier" ::: "memory")
#define BAR_LGKM() asm volatile("s_waitcnt lgkmcnt(0)\n\ts_barrier" ::: "memory")
#define PIN()      __builtin_amdgcn_sched_barrier(0)

__device__ __forceinline__ int sumpos(unsigned int w) {
    // sum of set-bit positions within a 32-bit word (exact)
    return __popc(w & 0xAAAAAAAAu) + (__popc(w & 0xCCCCCCCCu) << 1) +
           (__popc(w & 0xF0F0F0F0u) << 2) + (__popc(w & 0xFF00FF00u) << 3) +
           (__popc(w & 0xFFFF0000u) << 4);
}

__device__ __forceinline__ void dma16(const float* g, float* l)
{
    // lane writes 16B at (uniform l) + lane*16; global src is per-lane.
    __builtin_amdgcn_global_load_lds(
        (const __attribute__((address_space(1))) void*)g,
        (__attribute__((address_space(3))) void*)l,
        16, 0, 0);
}

__global__ __launch_bounds__(2 * ROWS)
void lif_kernel(const float* __restrict__ I, float* __restrict__ out)
{
    __shared__ float in2[2][ROWS * TC];            // 2 x 10,240 B, linear [64][40]
    __shared__ unsigned int bits[2][ROWS * 4];     // 2 x 1 KiB spike bits

    const int tid  = threadIdx.x;
    const int wv   = tid >> 6;       // 0 = compute wave, 1 = memory wave
    const int lane = tid & 63;
    const int rb   = blockIdx.x * ROWS;

    if (wv == 1) {
        // ------------------------- memory wave -------------------------
        const float* Ib = I   + (size_t)rb * Lsz;
        float*       Sb = out + (size_t)rb * Lsz;

        // DMA inst k stages LDS float4-slots [64k, 64k+64); slot s=64k+lane
        // -> (r=s/10, j'=s%10); global source float4 j = (j'<8)?j'^((r>>2)&7):j'
        // (XOR self-inverse, 16B blocks contiguous, coalescing preserved).
        int goff[V4];
#pragma unroll
        for (int k = 0; k < V4; ++k) {
            const int s  = k * 64 + lane;
            const int r  = s / 10;
            const int jp = s % 10;
            const int jg = (jp < 8) ? (jp ^ ((r >> 2) & 7)) : jp;
            goff[k] = r * Lsz + jg * 4;
        }
        auto dma = [&](int ch, int buf) {
#pragma unroll
            for (int k = 0; k < V4; ++k)
                dma16(Ib + goff[k] + ch * TC, &in2[buf][k * 256]);
        };
        auto expand_half = [&](int pair, int half) {   // 10 of 20 float4/row
            const unsigned int* bl = bits[pair & 1];
#pragma unroll
            for (int q = 0; q < 10; ++q) {
                const int it  = half * 10 + q;
                const int idx = it * ROWS + lane;
                const int r   = idx / 20;
                const int c4  = idx % 20;
                const unsigned int word = bl[r * 4 + (c4 >> 3)];
                const int bb = (c4 & 7) * 4;
                floatx4 vv = { (float)((word >> (bb + 0)) & 1u),
                               (float)((word >> (bb + 1)) & 1u),
                               (float)((word >> (bb + 2)) & 1u),
                               (float)((word >> (bb + 3)) & 1u) };
                __builtin_nontemporal_store(vv,
                    reinterpret_cast<floatx4*>(Sb + (size_t)r * Lsz + pair * 80 + c4 * 4));
            }
        };

        dma(0, 0);
        BAR_VM0();                   // chunk 0 resident
        for (int pr = 0; pr < 5; ++pr) {
            const int ch = 2 * pr;
            // phase A (compute scans ch from buf0): DMA ch+1 -> buf1
            dma(ch + 1, 1);
            PIN();                   // dma issued strictly BEFORE stores
            if (pr >= 1) expand_half(pr - 1, 0);
            PIN();                   // stores strictly before the waitcnt
            if (pr >= 1) { BAR_VM10(); } else { BAR_VM0(); }
            // phase B (compute scans ch+1 from buf1): DMA ch+2 -> buf0
            if (ch + 2 < 10) dma(ch + 2, 0);
            PIN();
            if (pr >= 1) expand_half(pr - 1, 1);
            PIN();
            if (pr >= 1) { BAR_VM10(); } else { BAR_VM0(); }
        }
        expand_half(4, 0); expand_half(4, 1);          // last pair (drains at endpgm)
    } else {
        // ------------------------- compute wave ------------------------
        float v = 0.0f, theta = 1.0f;
        int allow = 0, first = Lsz;
        int cnt_i = 0, swt_i = 0;            // integer-exact reductions
        unsigned int w0, w1, w2;
        const int gl = (lane >> 2) & 7;      // read-side XOR (matches source)

        // scan one 40-step chunk; gb = bit offset within pair (LITERAL 0/40)
        auto scan_chunk = [&](int buf, int t0, int gb) {
            const float* src = &in2[buf][lane * TC];
            float4 rgc4[V4];
#pragma unroll
            for (int j = 0; j < V4; ++j) {           // ds_read_b128, uniform banks
                const int jj = (j < 8) ? (j ^ gl) : j;
                rgc4[j] = *reinterpret_cast<const float4*>(src + jj * 4);
            }
            const float* in = reinterpret_cast<const float*>(rgc4);
#pragma unroll
            for (int c = 0; c < TC; ++c) {
                v = __builtin_fmaf(v, 0.95f, in[c]);       // v += -v/20 + I
                const int t = t0 + c;
                const bool hard = (v >= theta) & (t >= allow);
                v     = hard ? 0.0f : v;
                theta = __builtin_fmaf(theta, 0.98f, hard ? 0.52f : 0.02f);
                allow = hard ? (t + 6) : allow;            // 5 blocked steps
                const int cg = gb + c;                     // compile-time
                const unsigned int m = hard ? (1u << (cg & 31)) : 0u;
                if (cg < 32) w0 |= m; else if (cg < 64) w1 |= m; else w2 |= m;
            }
        };

        BAR_LGKM();                           // matches memory prologue barrier
        for (int pr = 0; pr < 5; ++pr) {
            w0 = w1 = w2 = 0u;
            scan_chunk(0, 2 * pr * TC, 0);
            BAR_LGKM();
            scan_chunk(1, (2 * pr + 1) * TC, TC);
            // pair-end reductions (exact) + publish bits for the memory wave
            const int tp = pr * 80;
            const int p0 = __popc(w0), p1 = __popc(w1), p2 = __popc(w2);
            const int cp = p0 + p1 + p2;
            cnt_i += cp;
            swt_i += tp * cp + sumpos(w0) + sumpos(w1) + 32 * p1 +
                     sumpos(w2) + 64 * p2;
            const int cand = w0 ? tp + (__ffs(w0) - 1)
                           : w1 ? tp + 32 + (__ffs(w1) - 1)
                           : w2 ? tp + 64 + (__ffs(w2) - 1) : Lsz;
            first = min(first, cand);
            *reinterpret_cast<uint4*>(&bits[pr & 1][lane * 4]) =
                make_uint4(w0, w1, w2, 0u);
            BAR_LGKM();
        }
        const int row = rb + lane;
        out[(size_t)Bsz * Lsz + row]       = (float)first;
        out[(size_t)Bsz * Lsz + Bsz + row] = (float)swt_i / ((float)cnt_i + 1e-6f);
    }
}

extern "C" void kernel_launch(void* const* d_in, const int* in_sizes, int n_in,
                              void* d_out, int out_size, void* d_ws, size_t ws_size,
                              hipStream_t stream)
{
    const float* I = (const float*)d_in[0];
    float* out = (float*)d_out;
    lif_kernel<<<dim3(Bsz / ROWS), dim3(2 * ROWS), 0, stream>>>(I, out);
}

// Round 18
// 35.416 us; speedup vs baseline: 1.1006x; 1.1006x over previous
//
#include <hip/hip_runtime.h>

// LIF forward scan, B=65536 rows x L=400 steps.  FINAL (= R14, session best).
// Outputs (concatenated float32 in d_out):
//   [0,              B*L)    spikes (exactly 0.0/1.0)
//   [B*L,        B*L + B)    hard_latency (first spike index, or L) as float
//   [B*L + B,  B*L + 2*B)    soft_latency = sum(s*t) / (sum(s) + 1e-6)
//
// Structure (evolved R1->R14):
//  - 2-wave producer/consumer blocks: wave0 scans 64 rows (serial in t,
//    fma-collapsed recurrences, spikes kept as register BITS, cnt/swt/first
//    via popcount/ffs -- integer-exact); wave1 stages input via
//    global_load_lds DMA (both-sides XOR swizzle, rule #21) and expands
//    bits -> dense sector-aligned NONTEMPORAL float4 stores.
//  - __syncthreads phase sync (counted-vmcnt variants R15/R16 raced or
//    cost VGPR/occupancy; the compiler drains are NOT binding here).
//  - 22.5KB LDS, 84 VGPR -> 4 blocks/CU (grid-capped), 8 waves/CU.
// 35.7us = 4.45 TB/s mixed HBM (71% of copy ceiling), traffic minimal.

constexpr int Bsz  = 65536;
constexpr int Lsz  = 400;
constexpr int ROWS = 64;            // rows per block (one per compute lane)
constexpr int TC   = 40;            // timesteps per chunk (phase)
constexpr int V4   = TC / 4;        // 10 float4 per chunk per row

typedef float floatx4 __attribute__((ext_vector_type(4)));

__device__ __forceinline__ int sumpos(unsigned int w) {
    // sum of set-bit positions within a 32-bit word (exact)
    return __popc(w & 0xAAAAAAAAu) + (__popc(w & 0xCCCCCCCCu) << 1) +
           (__popc(w & 0xF0F0F0F0u) << 2) + (__popc(w & 0xFF00FF00u) << 3) +
           (__popc(w & 0xFFFF0000u) << 4);
}

__device__ __forceinline__ void dma16(const float* g, float* l)
{
    // lane writes 16B at (uniform l) + lane*16; global src is per-lane.
    __builtin_amdgcn_global_load_lds(
        (const __attribute__((address_space(1))) void*)g,
        (__attribute__((address_space(3))) void*)l,
        16, 0, 0);
}

__global__ __launch_bounds__(2 * ROWS)
void lif_kernel(const float* __restrict__ I, float* __restrict__ out)
{
    __shared__ float in2[2][ROWS * TC];            // 2 x 10,240 B, linear [64][40]
    __shared__ unsigned int bits[2][ROWS * 4];     // 2 x 1 KiB spike bits

    const int tid  = threadIdx.x;
    const int wv   = tid >> 6;       // 0 = compute wave, 1 = memory wave
    const int lane = tid & 63;
    const int rb   = blockIdx.x * ROWS;

    if (wv == 1) {
        // ------------------------- memory wave -------------------------
        const float* Ib = I   + (size_t)rb * Lsz;
        float*       Sb = out + (size_t)rb * Lsz;

        // DMA inst k stages LDS float4-slots [64k, 64k+64); slot s=64k+lane
        // -> (r=s/10, j'=s%10); global source float4 j = (j'<8)?j'^((r>>2)&7):j'
        // (XOR self-inverse, 16B blocks contiguous, coalescing preserved).
        int goff[V4];
#pragma unroll
        for (int k = 0; k < V4; ++k) {
            const int s  = k * 64 + lane;
            const int r  = s / 10;
            const int jp = s % 10;
            const int jg = (jp < 8) ? (jp ^ ((r >> 2) & 7)) : jp;
            goff[k] = r * Lsz + jg * 4;
        }
        auto dma = [&](int ch, int buf) {
#pragma unroll
            for (int k = 0; k < V4; ++k)
                dma16(Ib + goff[k] + ch * TC, &in2[buf][k * 256]);
        };
        auto expand_half = [&](int pair, int half) {   // 10 of 20 float4/row
            const unsigned int* bl = bits[pair & 1];
#pragma unroll
            for (int q = 0; q < 10; ++q) {
                const int it  = half * 10 + q;
                const int idx = it * ROWS + lane;
                const int r   = idx / 20;
                const int c4  = idx % 20;
                const unsigned int word = bl[r * 4 + (c4 >> 3)];
                const int bb = (c4 & 7) * 4;
                floatx4 vv = { (float)((word >> (bb + 0)) & 1u),
                               (float)((word >> (bb + 1)) & 1u),
                               (float)((word >> (bb + 2)) & 1u),
                               (float)((word >> (bb + 3)) & 1u) };
                __builtin_nontemporal_store(vv,
                    reinterpret_cast<floatx4*>(Sb + (size_t)r * Lsz + pair * 80 + c4 * 4));
            }
        };

        dma(0, 0);
        __syncthreads();             // chunk 0 resident
        for (int pr = 0; pr < 5; ++pr) {
            const int ch = 2 * pr;
            // phase A (compute scans ch from buf0): DMA ch+1 -> buf1
            dma(ch + 1, 1);
            if (pr >= 1) expand_half(pr - 1, 0);
            __syncthreads();
            // phase B (compute scans ch+1 from buf1): DMA ch+2 -> buf0
            if (ch + 2 < 10) dma(ch + 2, 0);
            if (pr >= 1) expand_half(pr - 1, 1);
            __syncthreads();
        }
        expand_half(4, 0); expand_half(4, 1);          // last pair
    } else {
        // ------------------------- compute wave ------------------------
        float v = 0.0f, theta = 1.0f;
        int allow = 0, first = Lsz;
        int cnt_i = 0, swt_i = 0;            // integer-exact reductions
        unsigned int w0, w1, w2;
        const int gl = (lane >> 2) & 7;      // read-side XOR (matches source)

        // scan one 40-step chunk; gb = bit offset within pair (LITERAL 0/40)
        auto scan_chunk = [&](int buf, int t0, int gb) {
            const float* src = &in2[buf][lane * TC];
            float4 rgc4[V4];
#pragma unroll
            for (int j = 0; j < V4; ++j) {           // ds_read_b128, uniform banks
                const int jj = (j < 8) ? (j ^ gl) : j;
                rgc4[j] = *reinterpret_cast<const float4*>(src + jj * 4);
            }
            const float* in = reinterpret_cast<const float*>(rgc4);
#pragma unroll
            for (int c = 0; c < TC; ++c) {
                v = __builtin_fmaf(v, 0.95f, in[c]);       // v += -v/20 + I
                const int t = t0 + c;
                const bool hard = (v >= theta) & (t >= allow);
                v     = hard ? 0.0f : v;
                theta = __builtin_fmaf(theta, 0.98f, hard ? 0.52f : 0.02f);
                allow = hard ? (t + 6) : allow;            // 5 blocked steps
                const int cg = gb + c;                     // compile-time
                const unsigned int m = hard ? (1u << (cg & 31)) : 0u;
                if (cg < 32) w0 |= m; else if (cg < 64) w1 |= m; else w2 |= m;
            }
        };

        __syncthreads();                      // matches memory prologue barrier
        for (int pr = 0; pr < 5; ++pr) {
            w0 = w1 = w2 = 0u;
            scan_chunk(0, 2 * pr * TC, 0);
            __syncthreads();
            scan_chunk(1, (2 * pr + 1) * TC, TC);
            // pair-end reductions (exact) + publish bits for the memory wave
            const int tp = pr * 80;
            const int p0 = __popc(w0), p1 = __popc(w1), p2 = __popc(w2);
            const int cp = p0 + p1 + p2;
            cnt_i += cp;
            swt_i += tp * cp + sumpos(w0) + sumpos(w1) + 32 * p1 +
                     sumpos(w2) + 64 * p2;
            const int cand = w0 ? tp + (__ffs(w0) - 1)
                           : w1 ? tp + 32 + (__ffs(w1) - 1)
                           : w2 ? tp + 64 + (__ffs(w2) - 1) : Lsz;
            first = min(first, cand);
            *reinterpret_cast<uint4*>(&bits[pr & 1][lane * 4]) =
                make_uint4(w0, w1, w2, 0u);
            __syncthreads();
        }
        const int row = rb + lane;
        out[(size_t)Bsz * Lsz + row]       = (float)first;
        out[(size_t)Bsz * Lsz + Bsz + row] = (float)swt_i / ((float)cnt_i + 1e-6f);
    }
}

extern "C" void kernel_launch(void* const* d_in, const int* in_sizes, int n_in,
                              void* d_out, int out_size, void* d_ws, size_t ws_size,
                              hipStream_t stream)
{
    const float* I = (const float*)d_in[0];
    float* out = (float*)d_out;
    lif_kernel<<<dim3(Bsz / ROWS), dim3(2 * ROWS), 0, stream>>>(I, out);
}